// Round 1
// baseline (473.623 us; speedup 1.0000x reference)
//
#include <hip/hip_runtime.h>
#include <hip/hip_bf16.h>

#define B_      64
#define S_      4096
#define DIM_    256
#define DA_     64
#define NEG_    (-1e30f)
#define CHUNKS_ 16
#define ROWS_   256           // seq rows per chunk (4 rounds x 64)
#define PSTR_   258           // partial stride: m, l, acc[256]

typedef _Float16 half8 __attribute__((ext_vector_type(8)));
typedef float float4v __attribute__((ext_vector_type(4)));

// tanh(x) = 1 - 2/(exp(2x)+1); exact at +/-inf (exp->inf => 1, exp->0 => -1).
// err ~1e-6 << 2e-3 tolerance; replaces slow libm tanhf (no -ffast-math here).
__device__ __forceinline__ float tanh_fast(float x) {
    float e = __expf(2.0f * x);
    return 1.0f - 2.0f * __builtin_amdgcn_rcpf(e + 1.0f);
}

// Kernel 0 (unchanged): A (DIM x DA fp32) -> fp16 swizzled into MFMA fragment order,
// and detect mask encoding: flag=1 => int32 elements, flag=0 => 1-byte.
// at_sw index: ((nt*8+kb)*64 + lane)*8 + j  = a[d][n],
//   d = kb*32 + (lane>>4)*8 + j, n = nt*16 + (lane&15)
// R5 note: this layout serves BOTH the old B-operand use and the new A-operand
// (a^T) use — the (row/col <-> nrow, k <-> quad*8+j) mapping is symmetric.
__global__ __launch_bounds__(256) void prep_kernel(
    const float* __restrict__ a, const void* __restrict__ mask,
    _Float16* __restrict__ at_sw, int* __restrict__ flag)
{
    int idx = blockIdx.x * 256 + threadIdx.x;   // 0..16383
    int j    = idx & 7;
    int lane = (idx >> 3) & 63;
    int kbnt = idx >> 9;
    int kb   = kbnt & 7;
    int nt   = kbnt >> 3;
    int d  = kb * 32 + (lane >> 4) * 8 + j;
    int kf = nt * 16 + (lane & 15);
    at_sw[idx] = (_Float16)a[d * DA_ + kf];

    if (blockIdx.x == 0) {
        __shared__ int anynz;
        if (threadIdx.x == 0) anynz = 0;
        __syncthreads();
        const unsigned char* mb = (const unsigned char*)mask;
        int base = threadIdx.x * 4;   // scan first 1024 bytes
        int v = mb[base + 1] | mb[base + 2] | mb[base + 3];
        if (v) atomicOr(&anynz, 1);
        __syncthreads();
        if (threadIdx.x == 0) *flag = (anynz == 0) ? 1 : 0;
    }
}

// Kernel 1 (R5 rewrite): barrier-free per-wave streaming.
// e^T = a^T @ h^T  via mfma(A=a_frag, B=h_frag): h's B-fragment per lane is
// exactly one row's 8 contiguous dims -> load straight from global, no LDS
// staging, no stage barrier. D col = lane&15 = own row -> softmax + weighted
// accumulation stay in-lane/in-wave. Only 2 __syncthreads per block (prologue
// + final cross-wave merge). Old structure's HBM duty cycle ~1/3 -> ~1.
__global__ __launch_bounds__(256, 3) void fused_kernel(
    const float* __restrict__ h, const _Float16* __restrict__ at_sw,
    const float* __restrict__ bvec, const void* __restrict__ mask,
    const int* __restrict__ flag, float* __restrict__ part)
{
    __shared__ _Float16 asw[16384];      // 32 KiB a-fragments (L1-evict-proof)
    __shared__ float bv_l[64];
    __shared__ float red[4 * 256];       // cross-wave o merge
    __shared__ float ml[8];              // m,l per wave

    const int t = threadIdx.x;
    const int b = blockIdx.x >> 4;
    const int c = blockIdx.x & (CHUNKS_ - 1);
    const int wave = t >> 6;
    const int lane = t & 63;
    const int quad = lane >> 4;
    const int nrow = lane & 15;
    const bool int32enc = (*flag != 0);

    {   // prologue: a-fragments (32 KiB, L2-hot from prep) + b into LDS
        const uint4* g = (const uint4*)at_sw;
        uint4* l = (uint4*)asw;
        #pragma unroll
        for (int i = 0; i < 8; ++i) l[i * 256 + t] = g[i * 256 + t];
        if (t < 64) bv_l[t] = bvec[t];
    }
    __syncthreads();

    // this lane's row for every round: c*256 + round*64 + wave*16 + nrow
    const float* hl = h + (size_t)(b * S_ + c * ROWS_ + wave * 16 + nrow) * DIM_
                        + quad * 8;
    const long long mbase = (long long)b * S_ + c * ROWS_ + wave * 16 + nrow;

    float o[64];                         // own-row dims {kb*32 + quad*8 + j}
    #pragma unroll
    for (int i = 0; i < 64; ++i) o[i] = 0.f;
    float m_w = NEG_, l_w = 0.f;

    #pragma unroll 1
    for (int round = 0; round < 4; ++round) {
        const float* hr = hl + (size_t)round * 64 * DIM_;

        // ---- load own row's 256 dims, cvt fp32->fp16 fragments (RNE casts:
        //      keep the proven absmax; do NOT switch to cvt_pkrtz/RTZ) ----
        half8 hfr[8];
        #pragma unroll
        for (int kb = 0; kb < 8; ++kb) {
            float4 va = *(const float4*)(hr + kb * 32);
            float4 vb = *(const float4*)(hr + kb * 32 + 4);
            union { _Float16 hh[8]; half8 v; } pk;
            pk.hh[0] = (_Float16)va.x; pk.hh[1] = (_Float16)va.y;
            pk.hh[2] = (_Float16)va.z; pk.hh[3] = (_Float16)va.w;
            pk.hh[4] = (_Float16)vb.x; pk.hh[5] = (_Float16)vb.y;
            pk.hh[6] = (_Float16)vb.z; pk.hh[7] = (_Float16)vb.w;
            hfr[kb] = pk.v;
        }

        // ---- z^T[n][own row] = sum_d a[d][n] h[row][d] ----
        float4v acc[4];
        #pragma unroll
        for (int nt = 0; nt < 4; ++nt) acc[nt] = (float4v){0.f, 0.f, 0.f, 0.f};
        #pragma unroll
        for (int kb = 0; kb < 8; ++kb) {
            #pragma unroll
            for (int nt = 0; nt < 4; ++nt) {
                half8 af = *(const half8*)&asw[((nt * 8 + kb) * 64 + lane) * 8];
                acc[nt] = __builtin_amdgcn_mfma_f32_16x16x32_f16(af, hfr[kb], acc[nt], 0, 0, 0);
            }
        }

        // ---- e[own row]: lane holds n = nt*16 + quad*4 + r; sum over quads ----
        float p = 0.f;
        #pragma unroll
        for (int nt = 0; nt < 4; ++nt) {
            float4 bq = *(const float4*)&bv_l[nt * 16 + quad * 4];
            p += tanh_fast(acc[nt][0]) * bq.x;
            p += tanh_fast(acc[nt][1]) * bq.y;
            p += tanh_fast(acc[nt][2]) * bq.z;
            p += tanh_fast(acc[nt][3]) * bq.w;
        }
        p += __shfl_xor(p, 16);
        p += __shfl_xor(p, 32);

        // ---- mask + per-wave online softmax over its 16 rows ----
        long long mi = mbase + (long long)round * 64;
        int mv = int32enc ? ((const int*)mask)[mi]
                          : (int)((const unsigned char*)mask)[mi];
        float ev = mv ? NEG_ : p;

        float mx = ev;
        mx = fmaxf(mx, __shfl_xor(mx, 1));
        mx = fmaxf(mx, __shfl_xor(mx, 2));
        mx = fmaxf(mx, __shfl_xor(mx, 4));
        mx = fmaxf(mx, __shfl_xor(mx, 8));
        if (mx > m_w + 8.f) {            // defer-max (T13): rescale rarely
            float rs = __expf(m_w - mx);
            l_w *= rs;
            #pragma unroll
            for (int i = 0; i < 64; ++i) o[i] *= rs;
            m_w = mx;
        }
        float w_s = __expf(ev - m_w);    // bounded by e^8; masked -> 0
        float sm = w_s;
        sm += __shfl_xor(sm, 1);
        sm += __shfl_xor(sm, 2);
        sm += __shfl_xor(sm, 4);
        sm += __shfl_xor(sm, 8);
        l_w += sm;

        // ---- in-register weighted accumulation, own row only ----
        #pragma unroll
        for (int kb = 0; kb < 8; ++kb) {
            #pragma unroll
            for (int j = 0; j < 8; ++j)
                o[kb * 8 + j] = fmaf(w_s, (float)hfr[kb][j], o[kb * 8 + j]);
        }
    }

    // ---- intra-wave: sum o over the 16 nrow lanes (same quad => same dims) ----
    #pragma unroll
    for (int i = 0; i < 64; ++i) {
        o[i] += __shfl_xor(o[i], 1);
        o[i] += __shfl_xor(o[i], 2);
        o[i] += __shfl_xor(o[i], 4);
        o[i] += __shfl_xor(o[i], 8);
    }
    // each lane writes the 4 values assigned to its nrow (static reg indices —
    // runtime-indexed reg arrays go to scratch, rule #20)
    #pragma unroll
    for (int i = 0; i < 64; ++i) {
        if ((i >> 2) == nrow) {
            int d = (i >> 3) * 32 + quad * 8 + (i & 7);
            red[wave * 256 + d] = o[i];
        }
    }
    if (lane == 0) { ml[wave] = m_w; ml[4 + wave] = l_w; }
    __syncthreads();

    // ---- cross-wave softmax-merge + write chunk partial ----
    float M = fmaxf(fmaxf(ml[0], ml[1]), fmaxf(ml[2], ml[3]));
    float L = 0.f, O = 0.f;
    #pragma unroll
    for (int w2 = 0; w2 < 4; ++w2) {
        float sc = __expf(ml[w2] - M);
        L += ml[4 + w2] * sc;
        O = fmaf(red[w2 * 256 + t], sc, O);
    }
    float* pc = part + (size_t)(b * CHUNKS_ + c) * PSTR_;
    pc[2 + t] = O;
    if (t == 0) { pc[0] = M; pc[1] = L; }
}

// Kernel 2 (unchanged): merge per-chunk partials -> out[b][d]
__global__ __launch_bounds__(256) void merge_kernel(
    const float* __restrict__ part, float* __restrict__ out)
{
    const int b = blockIdx.x;
    const int t = threadIdx.x;
    const float* pb = part + (size_t)b * CHUNKS_ * PSTR_;
    float M = NEG_;
    #pragma unroll
    for (int c = 0; c < CHUNKS_; ++c) M = fmaxf(M, pb[c * PSTR_]);
    float L = 0.f, o = 0.f;
    #pragma unroll
    for (int c = 0; c < CHUNKS_; ++c) {
        float sc = __expf(pb[c * PSTR_] - M);
        L += pb[c * PSTR_ + 1] * sc;
        o += pb[c * PSTR_ + 2 + t] * sc;
    }
    out[b * DIM_ + t] = o / L;
}

extern "C" void kernel_launch(void* const* d_in, const int* in_sizes, int n_in,
                              void* d_out, int out_size, void* d_ws, size_t ws_size,
                              hipStream_t stream) {
    const float* h    = (const float*)d_in[0];
    const void*  mask = d_in[1];
    const float* a    = (const float*)d_in[2];
    const float* bvec = (const float*)d_in[3];
    float* out = (float*)d_out;

    char* ws = (char*)d_ws;
    _Float16* at_sw = (_Float16*)ws;              // 32,768 B
    int* flag       = (int*)(ws + 32768);
    float* part     = (float*)(ws + 36864);       // 64*16*258*4 ≈ 1 MiB

    prep_kernel<<<64, 256, 0, stream>>>(a, mask, at_sw, flag);
    fused_kernel<<<B_ * CHUNKS_, 256, 0, stream>>>(h, at_sw, bvec, mask, flag, part);
    merge_kernel<<<B_, 256, 0, stream>>>(part, out);
}

// Round 2
// 370.481 us; speedup vs baseline: 1.2784x; 1.2784x over previous
//
#include <hip/hip_runtime.h>
#include <hip/hip_bf16.h>

#define B_      64
#define S_      4096
#define DIM_    256
#define DA_     64
#define NEG_    (-1e30f)
#define CHUNKS_ 16
#define ROWS_   256           // seq rows per chunk (4 tiles x 64)
#define NBLK_   256           // persistent blocks (1 per CU, forced by 130 KiB LDS)
#define TILES_TOT_ 16         // 4 chunks x 4 tiles per block
#define LDW_    260           // floats per LDS row (256 + 4 pad: conflict-free, verified bank math)
#define PSTR_   258           // partial stride: m, l, acc[256]

typedef _Float16 half8 __attribute__((ext_vector_type(8)));
typedef float float4v __attribute__((ext_vector_type(4)));

// tanh(x) = 1 - 2/(exp(2x)+1); exact at +/-inf; err ~1e-6 << 2e-3 tol.
__device__ __forceinline__ float tanh_fast(float x) {
    float e = __expf(2.0f * x);
    return 1.0f - 2.0f * __builtin_amdgcn_rcpf(e + 1.0f);
}

// Kernel 0 (unchanged): A (DIM x DA fp32) -> fp16 swizzled into MFMA A-fragment
// order; detect mask encoding (flag=1 => int32 elements, flag=0 => 1-byte).
// at_sw index: ((nt*8+kb)*64 + lane)*8 + j = a[d][n],
//   d = kb*32 + (lane>>4)*8 + j, n = nt*16 + (lane&15)
__global__ __launch_bounds__(256) void prep_kernel(
    const float* __restrict__ a, const void* __restrict__ mask,
    _Float16* __restrict__ at_sw, int* __restrict__ flag)
{
    int idx = blockIdx.x * 256 + threadIdx.x;   // 0..16383
    int j    = idx & 7;
    int lane = (idx >> 3) & 63;
    int kbnt = idx >> 9;
    int kb   = kbnt & 7;
    int nt   = kbnt >> 3;
    int d  = kb * 32 + (lane >> 4) * 8 + j;
    int kf = nt * 16 + (lane & 15);
    at_sw[idx] = (_Float16)a[d * DA_ + kf];

    if (blockIdx.x == 0) {
        __shared__ int anynz;
        if (threadIdx.x == 0) anynz = 0;
        __syncthreads();
        const unsigned char* mb = (const unsigned char*)mask;
        int base = threadIdx.x * 4;   // scan first 1024 bytes
        int v = mb[base + 1] | mb[base + 2] | mb[base + 3];
        if (v) atomicOr(&anynz, 1);
        __syncthreads();
        if (threadIdx.x == 0) *flag = (anynz == 0) ? 1 : 0;
    }
}

// R6 fused kernel: wave-independent, barrier-free, global_load_lds-pipelined.
// - R5 post-mortem: per-lane o[64] spilled (VGPR=84, WRITE_SIZE 122 MB scratch).
//   Fix: per-lane state is acc0..3 (4 dims); the row<->dim transpose lives in
//   LDS, staged fp32 by global_load_lds (one padded row per instruction —
//   dest base is wave-uniform so padding is legal).
// - Each wave owns rows wave*16..+15 of every tile in BOTH buffers: no
//   cross-wave LDS hazard ever => zero __syncthreads in the whole kernel.
//   Per-wave (m,l,acc) partials merged in merge_kernel (64 partials/batch).
// - Persistent: block handles chunks {bid, bid+256, bid+512, bid+768} as a
//   flat 16-tile pipeline; 2-deep (dbuf) with per-wave vmcnt(0) between tiles.
// - a-fragments hoisted to 128 VGPRs once (1 wave/SIMD => 512-reg budget).
#define STAGE(ft_, sel_) do {                                                   \
    int cg_ = (int)blockIdx.x + ((ft_) >> 2) * NBLK_;                           \
    long long r0_ = (long long)(cg_ >> 4) * S_ + (long long)(cg_ & 15) * ROWS_  \
                  + ((ft_) & 3) * 64 + wave * 16;                               \
    const float* sp_ = h + r0_ * DIM_ + lane * 4;                               \
    _Pragma("unroll")                                                           \
    for (int i_ = 0; i_ < 16; ++i_) {                                           \
        __builtin_amdgcn_global_load_lds(                                       \
            (__attribute__((address_space(1))) void*)(sp_ + (size_t)i_ * DIM_), \
            (__attribute__((address_space(3))) void*)&buf[sel_][wave * 16 + i_][0], \
            16, 0, 0);                                                          \
    }                                                                           \
} while (0)

__global__ __launch_bounds__(256, 1) void fused_kernel(
    const float* __restrict__ h, const _Float16* __restrict__ at_sw,
    const float* __restrict__ bvec, const void* __restrict__ mask,
    const int* __restrict__ flag, float* __restrict__ part)
{
    __shared__ float buf[2][64][LDW_];   // 133,120 B => 1 block/CU

    const int t    = threadIdx.x;
    const int wave = t >> 6;
    const int lane = t & 63;
    const int quad = lane >> 4;
    const int nrow = lane & 15;
    const bool int32enc = (*flag != 0);

    // hoist a-fragments: af[nt][kb] = 32 x half8 = 128 VGPR (read once, L2-hot)
    half8 af[4][8];
    #pragma unroll
    for (int nt = 0; nt < 4; ++nt)
        #pragma unroll
        for (int kb = 0; kb < 8; ++kb)
            af[nt][kb] = *(const half8*)(at_sw + ((nt * 8 + kb) * 64 + lane) * 8);

    // b values for epilogue: bq[nt][r] = bvec[nt*16 + quad*4 + r]
    float4 bq[4];
    #pragma unroll
    for (int nt = 0; nt < 4; ++nt)
        bq[nt] = *(const float4*)(bvec + nt * 16 + quad * 4);

    float acc0 = 0.f, acc1 = 0.f, acc2 = 0.f, acc3 = 0.f;
    float m_w = NEG_, l_w = 0.f;

    STAGE(0, 0);
    asm volatile("s_waitcnt vmcnt(0)" ::: "memory");
    __builtin_amdgcn_sched_barrier(0);

    int cur = 0;
    #pragma unroll 1
    for (int ft = 0; ft < TILES_TOT_; ++ft) {
        int cg = (int)blockIdx.x + (ft >> 2) * NBLK_;
        long long row0 = (long long)(cg >> 4) * S_ + (long long)(cg & 15) * ROWS_
                       + (ft & 3) * 64 + wave * 16;

        // mask load FIRST so its wait is vmcnt(16) (stage loads stay in flight)
        long long mrow = row0 + nrow;
        int mv = int32enc ? ((const int*)mask)[mrow]
                          : (int)((const unsigned char*)mask)[mrow];

        if (ft < TILES_TOT_ - 1) STAGE(ft + 1, cur ^ 1);

        // ---- MFMA: z^T[n][own rows] from LDS fp32 (cvt) x reg a-fragments ----
        const float* hrow_l = &buf[cur][wave * 16 + nrow][0];
        float4v accm[4];
        #pragma unroll
        for (int nt = 0; nt < 4; ++nt) accm[nt] = (float4v){0.f, 0.f, 0.f, 0.f};
        #pragma unroll
        for (int kb = 0; kb < 8; ++kb) {
            float4 ha = *(const float4*)(hrow_l + kb * 32 + quad * 8);
            float4 hb2 = *(const float4*)(hrow_l + kb * 32 + quad * 8 + 4);
            union { _Float16 hh[8]; half8 v; } pk;
            pk.hh[0] = (_Float16)ha.x;  pk.hh[1] = (_Float16)ha.y;
            pk.hh[2] = (_Float16)ha.z;  pk.hh[3] = (_Float16)ha.w;
            pk.hh[4] = (_Float16)hb2.x; pk.hh[5] = (_Float16)hb2.y;
            pk.hh[6] = (_Float16)hb2.z; pk.hh[7] = (_Float16)hb2.w;
            #pragma unroll
            for (int nt = 0; nt < 4; ++nt)
                accm[nt] = __builtin_amdgcn_mfma_f32_16x16x32_f16(af[nt][kb], pk.v, accm[nt], 0, 0, 0);
        }

        // ---- e[own row]: lane holds n = nt*16 + quad*4 + r; reduce over quads ----
        float p = 0.f;
        #pragma unroll
        for (int nt = 0; nt < 4; ++nt) {
            p += tanh_fast(accm[nt][0]) * bq[nt].x;
            p += tanh_fast(accm[nt][1]) * bq[nt].y;
            p += tanh_fast(accm[nt][2]) * bq[nt].z;
            p += tanh_fast(accm[nt][3]) * bq[nt].w;
        }
        p += __shfl_xor(p, 16);
        p += __shfl_xor(p, 32);

        // ---- per-wave online softmax over its 16 rows ----
        float ev = mv ? NEG_ : p;
        float mx = ev;
        mx = fmaxf(mx, __shfl_xor(mx, 1));
        mx = fmaxf(mx, __shfl_xor(mx, 2));
        mx = fmaxf(mx, __shfl_xor(mx, 4));
        mx = fmaxf(mx, __shfl_xor(mx, 8));
        float m_new = fmaxf(m_w, mx);
        float rs  = __expf(m_w - m_new);       // first tile: exp(-1e30) = 0
        float w_s = __expf(ev - m_new);
        float sm = w_s;
        sm += __shfl_xor(sm, 1);
        sm += __shfl_xor(sm, 2);
        sm += __shfl_xor(sm, 4);
        sm += __shfl_xor(sm, 8);
        l_w = l_w * rs + sm;
        m_w = m_new;
        acc0 *= rs; acc1 *= rs; acc2 *= rs; acc3 *= rs;

        // ---- accumulate own 4 dims over the wave's 16 rows (fp32 from LDS) ----
        #pragma unroll
        for (int s = 0; s < 16; ++s) {
            float wv = __shfl(w_s, s);         // compile-time lane => v_readlane
            float4 hv = *(const float4*)(&buf[cur][wave * 16 + s][lane * 4]);
            acc0 = fmaf(wv, hv.x, acc0);
            acc1 = fmaf(wv, hv.y, acc1);
            acc2 = fmaf(wv, hv.z, acc2);
            acc3 = fmaf(wv, hv.w, acc3);
        }

        // ---- chunk boundary: write per-wave partial, reset state ----
        if ((ft & 3) == 3) {
            float* pc = part + (size_t)(cg * 4 + wave) * PSTR_;
            float4 o4 = make_float4(acc0, acc1, acc2, acc3);
            *(float4*)(pc + 2 + lane * 4) = o4;
            if (lane == 0) { pc[0] = m_w; pc[1] = l_w; }
            acc0 = acc1 = acc2 = acc3 = 0.f;
            m_w = NEG_; l_w = 0.f;
        }

        // next buffer staged + all LDS reads of this tile landed in regs
        asm volatile("s_waitcnt vmcnt(0) lgkmcnt(0)" ::: "memory");
        __builtin_amdgcn_sched_barrier(0);
        cur ^= 1;
    }
}

// Kernel 2: merge 64 per-wave partials (16 chunks x 4 waves) -> out[b][d]
__global__ __launch_bounds__(256) void merge_kernel(
    const float* __restrict__ part, float* __restrict__ out)
{
    const int b = blockIdx.x;
    const int t = threadIdx.x;
    const float* pb = part + (size_t)b * 64 * PSTR_;
    float M = NEG_;
    #pragma unroll
    for (int i = 0; i < 64; ++i) M = fmaxf(M, pb[i * PSTR_]);
    float L = 0.f, o = 0.f;
    #pragma unroll
    for (int i = 0; i < 64; ++i) {
        float sc = __expf(pb[i * PSTR_] - M);
        L += pb[i * PSTR_ + 1] * sc;
        o += pb[i * PSTR_ + 2 + t] * sc;
    }
    out[b * DIM_ + t] = o / L;
}

extern "C" void kernel_launch(void* const* d_in, const int* in_sizes, int n_in,
                              void* d_out, int out_size, void* d_ws, size_t ws_size,
                              hipStream_t stream) {
    const float* h    = (const float*)d_in[0];
    const void*  mask = d_in[1];
    const float* a    = (const float*)d_in[2];
    const float* bvec = (const float*)d_in[3];
    float* out = (float*)d_out;

    char* ws = (char*)d_ws;
    _Float16* at_sw = (_Float16*)ws;              // 32,768 B
    int* flag       = (int*)(ws + 32768);
    float* part     = (float*)(ws + 36864);       // 4096 partials * 258 * 4 B ~= 4 MiB

    prep_kernel<<<64, 256, 0, stream>>>(a, mask, at_sw, flag);
    fused_kernel<<<NBLK_, 256, 0, stream>>>(h, at_sw, bvec, mask, flag, part);
    merge_kernel<<<B_, 256, 0, stream>>>(part, out);
}